// Round 2
// baseline (1939.720 us; speedup 1.0000x reference)
//
#include <hip/hip_runtime.h>

// Problem constants
#define NTOK 65536          // B*S = 16*4096 tokens
#define DDIM 64             // embedding dim
#define KCB  4096           // codebook size
#define IDXOFF  (NTOK * DDIM)          // 4194304: indices start
#define LOSSOFF (NTOK * DDIM + NTOK)   // 4259840: scalar loss

// Empty asm barrier: keeps a rounded fp32 value opaque so the compiler cannot
// contract the preceding mul into a following add (must match numpy's
// round-square-then-add exactly).
__device__ __forceinline__ float opaque(float x) {
    asm volatile("" : "+v"(x));
    return x;
}

// numpy pairwise_sum for n=64 contiguous floats of squares of src[0..63]:
// 8 accumulators r[j] over stride-8 lanes, combined ((r0+r1)+(r2+r3))+((r4+r5)+(r6+r7)).
__device__ __forceinline__ float np_sumsq64(const float* __restrict__ v) {
    float r[8];
#pragma unroll
    for (int j = 0; j < 8; ++j) r[j] = opaque(v[j] * v[j]);
#pragma unroll
    for (int i = 1; i < 8; ++i)
#pragma unroll
        for (int j = 0; j < 8; ++j) r[j] += opaque(v[8 * i + j] * v[8 * i + j]);
    return ((r[0] + r[1]) + (r[2] + r[3])) + ((r[4] + r[5]) + (r[6] + r[7]));
}

// ---------------- Kernel A: codebook squared norms + zero loss accum ----------------
__global__ void k_enorm(const float* __restrict__ emb, float* __restrict__ e2,
                        double* __restrict__ lossacc) {
    int k = blockIdx.x * blockDim.x + threadIdx.x;
    if (k == 0) *lossacc = 0.0;
    if (k < KCB) {
        float row[DDIM];
        const float4* r4 = (const float4*)(emb + (size_t)k * DDIM);
#pragma unroll
        for (int i = 0; i < DDIM / 4; ++i) {
            float4 v = r4[i];
            row[4*i+0] = v.x; row[4*i+1] = v.y; row[4*i+2] = v.z; row[4*i+3] = v.w;
        }
        e2[k] = np_sumsq64(row);
    }
}

// ---------------- Kernel B: argmin + gather + quantized write + loss ----------------
// Grid: 256 blocks (256 tokens each) x 1024 threads.
// Thread (t = tid&255, q = tid>>8): token = blk*256+t, scans K-quarter q.
// Score replicates numpy fp32 exactly:
//   s_k = fl( fl(z2 + e2_k) - m_k ),  m_k = seqFMA_j (2*z_j)*e_{k,j}
// (python: z2[:,None] + e2[None,:] - 2.0*flat_z @ emb.T, with (2.0*flat_z)@emb.T
//  by precedence; BLAS accumulates each element as one sequential fp32 FMA chain.)
__global__ __launch_bounds__(1024) void k_vq(
    const float* __restrict__ z, const float* __restrict__ emb,
    const float* __restrict__ e2, float* __restrict__ out,
    double* __restrict__ lossacc) {
    __shared__ float sc[1024];
    __shared__ int   si[1024];
    __shared__ int   bidx_s[256];
    __shared__ float red[1024];

    const int tid = threadIdx.x;
    const int t   = tid & 255;
    const int q   = tid >> 8;
    const int token = blockIdx.x * 256 + t;

    // Load this token's z row into registers.
    float zr[DDIM];
    const float4* z4 = (const float4*)(z + (size_t)token * DDIM);
#pragma unroll
    for (int i = 0; i < DDIM / 4; ++i) {
        float4 v = z4[i];
        zr[4*i+0] = v.x; zr[4*i+1] = v.y; zr[4*i+2] = v.z; zr[4*i+3] = v.w;
    }

    // z2 exactly as numpy pairwise sum of fp32 squares (constant per token).
    const float z2t = np_sumsq64(zr);

    // Pre-double z (exact) for the (2*z)@emb.T FMA chain.
#pragma unroll
    for (int j = 0; j < DDIM; ++j) zr[j] = zr[j] + zr[j];

    const int kbase = q * (KCB / 4);
    float best = 3.0e38f;
    int   bi   = kbase;
    const float* ep = emb + (size_t)kbase * DDIM;
    for (int k = 0; k < KCB / 4; k += 2) {
        const float* e0p = ep + (size_t)k * DDIM;
        const float* e1p = e0p + DDIM;
        float m0 = 0.f, m1 = 0.f;   // sequential FMA chains (BLAS k-order)
#pragma unroll
        for (int j = 0; j < DDIM; ++j) {
            m0 = fmaf(zr[j], e0p[j], m0);
            m1 = fmaf(zr[j], e1p[j], m1);
        }
        float s0 = (z2t + e2[kbase + k])     - m0;  // two fp32 roundings, as numpy
        float s1 = (z2t + e2[kbase + k + 1]) - m1;
        // strict < with ascending k == first-occurrence argmin (np semantics)
        if (s0 < best) { best = s0; bi = kbase + k; }
        if (s1 < best) { best = s1; bi = kbase + k + 1; }
    }
    sc[tid] = best;
    si[tid] = bi;
    __syncthreads();

    // Combine the 4 quarters (ascending q == ascending k -> first-min ties).
    if (q == 0) {
        float b  = sc[t];
        int   bx = si[t];
#pragma unroll
        for (int qq = 1; qq < 4; ++qq) {
            float s2 = sc[qq * 256 + t];
            int   i2 = si[qq * 256 + t];
            if (s2 < b) { b = s2; bx = i2; }
        }
        bidx_s[t] = bx;
        out[IDXOFF + token] = (float)bx;  // whole d_out is read as fp32
    }
    __syncthreads();

    // Distributed epilogue: 256x64 quantized values (coalesced float4 stores)
    // + (q-z)^2 accumulation for the loss.
    float lsum = 0.f;
    const size_t obase = (size_t)blockIdx.x * 256 * DDIM;
#pragma unroll
    for (int it = 0; it < 4; ++it) {
        int f  = it * 1024 + tid;   // 0..4095 float4 slots (256 tok * 16)
        int tt = f >> 4;            // token within block
        int cc = f & 15;            // float4 chunk within row
        int idx = bidx_s[tt];
        float4 qv = ((const float4*)(emb + (size_t)idx * DDIM))[cc];
        float4 zv = ((const float4*)(z + obase + (size_t)tt * DDIM))[cc];
        ((float4*)(out + obase))[f] = qv;
        float dx = qv.x - zv.x, dy = qv.y - zv.y;
        float dz = qv.z - zv.z, dw = qv.w - zv.w;
        lsum += dx * dx + dy * dy + dz * dz + dw * dw;
    }
    red[tid] = lsum;
    __syncthreads();
    for (int s = 512; s > 0; s >>= 1) {
        if (tid < s) red[tid] += red[tid + s];
        __syncthreads();
    }
    if (tid == 0) atomicAdd(lossacc, (double)red[0]);
}

// ---------------- Kernel C: finalize loss ----------------
__global__ void k_fin(const double* __restrict__ lossacc, float* __restrict__ out) {
    // vq_loss = e_latent + q_latent = 2 * mean((q - z)^2)
    out[LOSSOFF] = (float)(2.0 * (*lossacc) / (double)(NTOK * DDIM));
}

extern "C" void kernel_launch(void* const* d_in, const int* in_sizes, int n_in,
                              void* d_out, int out_size, void* d_ws, size_t ws_size,
                              hipStream_t stream) {
    const float* z   = (const float*)d_in[0];   // [16,4096,64] fp32
    const float* emb = (const float*)d_in[1];   // [4096,64] fp32
    float* out = (float*)d_out;
    float*  e2      = (float*)d_ws;                      // 4096 floats
    double* lossacc = (double*)((char*)d_ws + 16384);    // 8 bytes, aligned

    hipLaunchKernelGGL(k_enorm, dim3(16), dim3(256), 0, stream, emb, e2, lossacc);
    hipLaunchKernelGGL(k_vq, dim3(NTOK / 256), dim3(1024), 0, stream,
                       z, emb, e2, out, lossacc);
    hipLaunchKernelGGL(k_fin, dim3(1), dim3(1), 0, stream, lossacc, out);
}

// Round 3
// 544.418 us; speedup vs baseline: 3.5629x; 3.5629x over previous
//
#include <hip/hip_runtime.h>

// Problem constants
#define NTOK 65536          // B*S = 16*4096 tokens
#define DDIM 64             // embedding dim
#define KCB  4096           // codebook size
#define MB   128            // tokens per block
#define NB   128            // codes per tile
#define IDXOFF  (NTOK * DDIM)          // 4194304: indices start
#define LOSSOFF (NTOK * DDIM + NTOK)   // 4259840: scalar loss

// Empty asm barrier: keeps a rounded fp32 value opaque so the compiler cannot
// contract the preceding mul into a following add (must match numpy's
// round-square-then-add exactly).
__device__ __forceinline__ float opaque(float x) {
    asm volatile("" : "+v"(x));
    return x;
}

// numpy pairwise_sum for n=64 contiguous floats of squares of src[0..63]:
// 8 accumulators r[j] over stride-8 lanes, ((r0+r1)+(r2+r3))+((r4+r5)+(r6+r7)).
__device__ __forceinline__ float np_sumsq64(const float* __restrict__ v) {
    float r[8];
#pragma unroll
    for (int j = 0; j < 8; ++j) r[j] = opaque(v[j] * v[j]);
#pragma unroll
    for (int i = 1; i < 8; ++i)
#pragma unroll
        for (int j = 0; j < 8; ++j) r[j] += opaque(v[8 * i + j] * v[8 * i + j]);
    return ((r[0] + r[1]) + (r[2] + r[3])) + ((r[4] + r[5]) + (r[6] + r[7]));
}

// ---------------- Kernel A: codebook squared norms + zero loss accum ----------------
__global__ void k_enorm(const float* __restrict__ emb, float* __restrict__ e2,
                        double* __restrict__ lossacc) {
    int k = blockIdx.x * blockDim.x + threadIdx.x;
    if (k == 0) *lossacc = 0.0;
    if (k < KCB) {
        float row[DDIM];
        const float4* r4 = (const float4*)(emb + (size_t)k * DDIM);
#pragma unroll
        for (int i = 0; i < DDIM / 4; ++i) {
            float4 v = r4[i];
            row[4*i+0] = v.x; row[4*i+1] = v.y; row[4*i+2] = v.z; row[4*i+3] = v.w;
        }
        e2[k] = np_sumsq64(row);
    }
}

// ---------------- Kernel B: LDS-tiled register-blocked GEMM-argmin ----------------
// Grid: 512 blocks x 1024 threads (tx = tid&31, ty = tid>>5).
// Block owns MB=128 tokens; loops over 32 tiles of NB=128 codes.
// zs: [k][m] (transposed, pre-doubled 2*z). es: [k][n] per tile.
// Thread computes a 4x4 (m x n) accumulator tile; each accumulator is ONE
// sequential fmaf chain over k=0..63 in order -> matches BLAS/np fp32 exactly:
//   s = fl( fl(z2 + e2_n) - m_n ),  m_n = seqFMA_k (2*z_k)*e_{n,k}
__global__ __launch_bounds__(1024) void k_vq(
    const float* __restrict__ z, const float* __restrict__ emb,
    const float* __restrict__ e2g, float* __restrict__ out,
    double* __restrict__ lossacc) {
    __shared__ float zs[DDIM * MB];    // 32 KB; later aliased: bestv[m*33+tx]
    __shared__ float es[DDIM * NB];    // 32 KB; later aliased: besti[m*33+tx]
    __shared__ float z2s[MB];
    __shared__ float e2t[NB];
    __shared__ float red[1024];
    __shared__ int   bidx_s[MB];

    const int tid = threadIdx.x;
    const int tx  = tid & 31;
    const int ty  = tid >> 5;
    const size_t zbase = (size_t)blockIdx.x * MB * DDIM;

    // ---- Stage z tile: coalesced float4 global reads -> transposed doubled LDS ----
#pragma unroll
    for (int it = 0; it < 2; ++it) {
        int f  = it * 1024 + tid;       // 0..2047 float4 slots (128 tok * 16)
        int tt = f >> 4;                // token within block
        int cc = f & 15;                // float4 chunk (covers k = 4cc..4cc+3)
        float4 v = ((const float4*)(z + zbase))[f];
        zs[(4*cc+0) * MB + tt] = v.x + v.x;   // exact doubling
        zs[(4*cc+1) * MB + tt] = v.y + v.y;
        zs[(4*cc+2) * MB + tt] = v.z + v.z;
        zs[(4*cc+3) * MB + tt] = v.w + v.w;
    }
    __syncthreads();

    // ---- z2 per token (np pairwise of ORIGINAL z = 0.5*zs, exact halving) ----
    if (tid < MB) {
        float r8[8];
#pragma unroll
        for (int j = 0; j < 8; ++j) {
            float v = 0.5f * zs[j * MB + tid];
            r8[j] = opaque(v * v);
        }
#pragma unroll
        for (int i = 1; i < 8; ++i)
#pragma unroll
            for (int j = 0; j < 8; ++j) {
                float v = 0.5f * zs[(8*i+j) * MB + tid];
                r8[j] += opaque(v * v);
            }
        z2s[tid] = ((r8[0]+r8[1])+(r8[2]+r8[3])) + ((r8[4]+r8[5])+(r8[6]+r8[7]));
    }
    __syncthreads();

    float z2l[4];
#pragma unroll
    for (int a = 0; a < 4; ++a) z2l[a] = z2s[ty*4 + a];

    float best[4] = {3.0e38f, 3.0e38f, 3.0e38f, 3.0e38f};
    int   bidx[4] = {0, 0, 0, 0};

    for (int n0 = 0; n0 < KCB; n0 += NB) {
        __syncthreads();   // previous tile's es reads done before overwrite
        // ---- Stage e tile (transposed) + e2 tile ----
#pragma unroll
        for (int it = 0; it < 2; ++it) {
            int f  = it * 1024 + tid;   // 0..2047 float4 slots (128 rows * 16)
            int rr = f >> 4;            // code row within tile
            int cc = f & 15;
            float4 v = ((const float4*)(emb + (size_t)(n0 + rr) * DDIM))[cc];
            es[(4*cc+0) * NB + rr] = v.x;
            es[(4*cc+1) * NB + rr] = v.y;
            es[(4*cc+2) * NB + rr] = v.z;
            es[(4*cc+3) * NB + rr] = v.w;
        }
        if (tid < NB) e2t[tid] = e2g[n0 + tid];
        __syncthreads();

        // ---- 4x4 register outer product; sequential k chains (np order) ----
        float acc[4][4] = {{0.f,0.f,0.f,0.f},{0.f,0.f,0.f,0.f},
                           {0.f,0.f,0.f,0.f},{0.f,0.f,0.f,0.f}};
#pragma unroll
        for (int k = 0; k < DDIM; ++k) {
            float4 zf = *(const float4*)&zs[k * MB + ty*4];  // broadcast across tx
            float4 ef = *(const float4*)&es[k * NB + tx*4];
            float za[4] = {zf.x, zf.y, zf.z, zf.w};
            float ea[4] = {ef.x, ef.y, ef.z, ef.w};
#pragma unroll
            for (int a = 0; a < 4; ++a)
#pragma unroll
                for (int b = 0; b < 4; ++b)
                    acc[a][b] = fmaf(za[a], ea[b], acc[a][b]);
        }
        // ---- Scores + running argmin (ascending n, strict < = np first-min) ----
#pragma unroll
        for (int b = 0; b < 4; ++b) {
            float e2v = e2t[tx*4 + b];
            int   n   = n0 + tx*4 + b;
#pragma unroll
            for (int a = 0; a < 4; ++a) {
                float s = (z2l[a] + e2v) - acc[a][b];   // two fp32 roundings, as np
                if (s < best[a]) { best[a] = s; bidx[a] = n; }
            }
        }
    }
    __syncthreads();   // all es/zs reads done; safe to alias

    // ---- Cross-thread combine: lexicographic (val, idx) per token ----
    float* bestv_s = zs;            // [m*33 + tx], 128*33 <= 8192 floats
    int*   besti_s = (int*)es;
#pragma unroll
    for (int a = 0; a < 4; ++a) {
        int m = ty*4 + a;
        bestv_s[m*33 + tx] = best[a];
        besti_s[m*33 + tx] = bidx[a];
    }
    __syncthreads();
    if (tid < MB) {
        float b  = bestv_s[tid*33 + 0];
        int   bi = besti_s[tid*33 + 0];
#pragma unroll
        for (int x = 1; x < 32; ++x) {
            float v = bestv_s[tid*33 + x];
            int   i = besti_s[tid*33 + x];
            if (v < b || (v == b && i < bi)) { b = v; bi = i; }
        }
        bidx_s[tid] = bi;
        out[IDXOFF + blockIdx.x * MB + tid] = (float)bi;  // d_out read as fp32
    }
    __syncthreads();

    // ---- Epilogue: quantized gather-write (coalesced float4) + loss ----
    float lsum = 0.f;
#pragma unroll
    for (int it = 0; it < 2; ++it) {
        int f  = it * 1024 + tid;   // 0..2047 float4 slots
        int tt = f >> 4;
        int cc = f & 15;
        int idx = bidx_s[tt];
        float4 qv = ((const float4*)(emb + (size_t)idx * DDIM))[cc];
        float4 zv = ((const float4*)(z + zbase))[f];
        ((float4*)(out + zbase))[f] = qv;
        float dx = qv.x - zv.x, dy = qv.y - zv.y;
        float dz = qv.z - zv.z, dw = qv.w - zv.w;
        lsum += dx * dx + dy * dy + dz * dz + dw * dw;
    }
    red[tid] = lsum;
    __syncthreads();
    for (int s = 512; s > 0; s >>= 1) {
        if (tid < s) red[tid] += red[tid + s];
        __syncthreads();
    }
    if (tid == 0) atomicAdd(lossacc, (double)red[0]);
}

// ---------------- Kernel C: finalize loss ----------------
__global__ void k_fin(const double* __restrict__ lossacc, float* __restrict__ out) {
    // vq_loss = e_latent + q_latent = 2 * mean((q - z)^2)
    out[LOSSOFF] = (float)(2.0 * (*lossacc) / (double)(NTOK * DDIM));
}

extern "C" void kernel_launch(void* const* d_in, const int* in_sizes, int n_in,
                              void* d_out, int out_size, void* d_ws, size_t ws_size,
                              hipStream_t stream) {
    const float* z   = (const float*)d_in[0];   // [16,4096,64] fp32
    const float* emb = (const float*)d_in[1];   // [4096,64] fp32
    float* out = (float*)d_out;
    float*  e2      = (float*)d_ws;                      // 4096 floats
    double* lossacc = (double*)((char*)d_ws + 16384);    // 8 bytes, aligned

    hipLaunchKernelGGL(k_enorm, dim3(16), dim3(256), 0, stream, emb, e2, lossacc);
    hipLaunchKernelGGL(k_vq, dim3(NTOK / MB), dim3(1024), 0, stream,
                       z, emb, e2, out, lossacc);
    hipLaunchKernelGGL(k_fin, dim3(1), dim3(1), 0, stream, lossacc, out);
}